// Round 10
// baseline (769.627 us; speedup 1.0000x reference)
//
#include <hip/hip_runtime.h>

// 4-layer 5-point cross-stencil CNN, implicit GEMM on MFMA (MI355X gfx950).
// Round 10: LDS-free gmid, TLP over ILP.
//   Evidence R3/R5/R6: all non-spilled LDS-panel variants stall at 17-20%
//   MfmaUtil with 8-12 waves/CU (pipes serialize per wave). R7-R9: register
//   pipelines spill. Fix: drop the A-panel entirely.
//   - Activations in j-PADDED device-global buffers: stride 257 px, one zero
//     column at j=256 serves both j=-1 (previous row's pad) and j=+16 halos;
//     128-elem lead pad covers (b=0,i=0,j=-1). prep zeroes pads every launch.
//   - gmid reads A-frags straight from global (L1/L2-cached), B from the
//     K-major weight table. No LDS, no barriers. i-halo = 2 wave-uniform
//     branch-skips (A-row==0 -> skip the MFMAs).
//   - Wave = 2 rows x 4 n-frags: acc 32 regs, ~85 total, (256,4) cap 128 ->
//     no spill possible, 16 waves/CU.
//   - k-loop kc-outer/tap-inner (+ weight layout [kc][tap][oc][32]) so
//     c/l/r taps re-read the same lines within ~3 k-steps -> L1 hits.
// MFMA 16x16x32_f16 layouts (verified rounds 3-9):
//   A[m=lane&15][k=quad*8+j], B[n=lane&15][k=quad*8+j], C: col=lane&15,
//   row=quad*4+reg.   Taps: 0=c,1=up,2=down,3=left,4=right.

#define BB   8
#define HH   256
#define WW   256
#define APX  257                         // padded j-stride (px)

typedef _Float16 f16x8 __attribute__((ext_vector_type(8)));
typedef float    f32x4 __attribute__((ext_vector_type(4)));

#define AELEMS ((size_t)2048 * APX * 128)
// Padded activation buffers: [lead 128][2048 rows][257 px][128 ch].
__device__ _Float16 A1g[128 + 2048 * APX * 128];
__device__ _Float16 A2g[128 + 2048 * APX * 128];

// fp16 weight tables (rewritten every launch by prep).
__device__ _Float16 W1g[128 * 32];       // [oc][k], k=tap*6+ic, 30..31 = 0
__device__ _Float16 W2g[20 * 128 * 32];  // [ks=kc*5+tap][oc][icb]
__device__ _Float16 W3g[20 * 128 * 32];
__device__ _Float16 W4g[5 * 16 * 128];   // [tap][oc(pad16)][ic]

__global__ void prep(const float* __restrict__ w1, const float* __restrict__ w2,
                     const float* __restrict__ w3, const float* __restrict__ w4)
{
    int idx = blockIdx.x * 256 + threadIdx.x;
    if (idx < 81920) {                                  // W2g [kc*5+tap][oc][icb]
        int icb = idx & 31, oc = (idx >> 5) & 127, ks = idx >> 12;
        int tap = ks % 5, kc = ks / 5;
        W2g[idx] = (_Float16)w2[(oc * 128 + kc * 32 + icb) * 5 + tap];
    } else if (idx < 163840) {                          // W3g
        int k = idx - 81920;
        int icb = k & 31, oc = (k >> 5) & 127, ks = k >> 12;
        int tap = ks % 5, kc = ks / 5;
        W3g[k] = (_Float16)w3[(oc * 128 + kc * 32 + icb) * 5 + tap];
    } else if (idx < 174080) {                          // W4g [tap][oc16][ic]
        int k = idx - 163840;
        int t = k / 2048, oc = (k >> 7) & 15, ic = k & 127;
        W4g[k] = (_Float16)((oc < 6) ? w4[(oc * 128 + ic) * 5 + t] : 0.f);
    } else if (idx < 178176) {                          // W1g
        int k = idx - 174080;
        int kk = k & 31, oc = k >> 5;
        float v = 0.f;
        if (kk < 30) {
            int tap = (kk * 43) >> 8;                   // kk/6 for kk<30
            int ic = kk - 6 * tap;
            v = w1[(oc * 6 + ic) * 5 + tap];
        }
        W1g[k] = (_Float16)v;
    } else if (idx < 178176 + 2 * (2048 * 128 + 128)) { // zero pads (every launch)
        int k = idx - 178176;
        const int per = 2048 * 128 + 128;
        _Float16* A = (k >= per) ? A2g : A1g;
        int p = (k >= per) ? (k - per) : k;
        if (p < 128) A[p] = (_Float16)0.f;              // lead pad
        else {
            int q = p - 128, row = q >> 7, c = q & 127; // j=256 column
            A[128 + ((size_t)row * APX + 256) * 128 + c] = (_Float16)0.f;
        }
    }
}

// ---------------- L1: MFMA, K=32 (tap*6+ic, padded). NCHW fp32 -> padded NHWC.
__global__ __launch_bounds__(256, 3) void g1(
    const float* __restrict__ x, const float* __restrict__ bias)
{
    _Float16* outp = A1g + 128;
    __shared__ _Float16 Ap[128 * 40];
    const int tid = threadIdx.x;
    const int j0 = blockIdx.x * 16, i0 = blockIdx.y * 8, b = blockIdx.z;
    const int px = tid & 127, half = tid >> 7;
    const int pr = px >> 4, pp = px & 15;
#pragma unroll
    for (int it = 0; it < 16; ++it) {
        int k = it * 2 + half;
        float v = 0.f;
        if (k < 30) {
            int tap = (k * 43) >> 8, ic = k - 6 * tap;
            int di = (tap == 1) ? -1 : ((tap == 2) ? 1 : 0);
            int dj = (tap == 3) ? -1 : ((tap == 4) ? 1 : 0);
            int gi = i0 + pr + di, gj = j0 + pp + dj;
            if (((unsigned)gi < 256u) && ((unsigned)gj < 256u))
                v = x[(((size_t)b * 6 + ic) * 256 + gi) * 256 + gj];
        }
        Ap[px * 40 + k] = (_Float16)v;
    }
    __syncthreads();

    const int lane = tid & 63, w = tid >> 6, l16 = lane & 15, quad = lane >> 4;
    f32x4 acc[2][8] = {};
    f16x8 a0 = *(const f16x8*)&Ap[((2 * w + 0) * 16 + l16) * 40 + quad * 8];
    f16x8 a1 = *(const f16x8*)&Ap[((2 * w + 1) * 16 + l16) * 40 + quad * 8];
#pragma unroll
    for (int nf = 0; nf < 8; ++nf) {
        f16x8 bf = *(const f16x8*)&W1g[(nf * 16 + l16) * 32 + quad * 8];
        acc[0][nf] = __builtin_amdgcn_mfma_f32_16x16x32_f16(a0, bf, acc[0][nf], 0, 0, 0);
        acc[1][nf] = __builtin_amdgcn_mfma_f32_16x16x32_f16(a1, bf, acc[1][nf], 0, 0, 0);
    }
#pragma unroll
    for (int mf = 0; mf < 2; ++mf) {
        const size_t rowb = ((size_t)b * 256 + i0 + 2 * w + mf) * APX + j0;
#pragma unroll
        for (int nf = 0; nf < 8; ++nf) {
            const float bv = bias[nf * 16 + l16];
#pragma unroll
            for (int r = 0; r < 4; ++r)
                outp[(rowb + quad * 4 + r) * 128 + nf * 16 + l16] =
                    (_Float16)fmaxf(acc[mf][nf][r] + bv, 0.f);
        }
    }
}

// ---------------- middle layers: LDS-free. Block 256 thr = 4 waves.
// Tile: 4 rows x 16 px x 128 oc. Wave(mg=w&1, ng=w>>1): rows {2mg,2mg+1},
// oc n0=ng*64 (4 n-frags). acc 2x4x4 = 32 regs. A direct from padded global.
template<int LAYER>
__global__ __launch_bounds__(256, 4) void gmid(const float* __restrict__ bias)
{
    const _Float16* wt = (LAYER == 2) ? W2g : W3g;
    const _Float16* in = ((LAYER == 2) ? A1g : A2g) + 128;
    _Float16* outp     = ((LAYER == 2) ? A2g : A1g) + 128;
    const int tid = threadIdx.x;
    const int j0 = blockIdx.x * 16, i0 = blockIdx.y * 4, b = blockIdx.z;
    const int lane = tid & 63, w = tid >> 6;
    const int l16 = lane & 15, quad = lane >> 4;
    const int mg = w & 1, ng = w >> 1;
    const int n0 = ng * 64;
    const int r0 = 2 * mg;                       // wave's first row in tile

    // Row base pointers for rows i0+r0-1 .. i0+r0+2 (wave-uniform).
    const _Float16* rb[4];
#pragma unroll
    for (int t = 0; t < 4; ++t)
        rb[t] = in + (size_t)(b * 256 + i0 + r0 - 1 + t) * APX * 128;
    // Per-lane element offsets for dj = -1,0,+1 (pads absorb OOB j).
    int loff[3];
#pragma unroll
    for (int dp = 0; dp < 3; ++dp)
        loff[dp] = (j0 + l16 + dp - 1) * 128 + quad * 8;
    const _Float16* wb = wt + (size_t)(n0 + l16) * 32 + quad * 8;

    const bool topok = (i0 + r0) > 0;            // row r0-1 exists
    const bool botok = (i0 + r0 + 2) < 256;      // row r0+2 exists

    f32x4 acc[2][4] = {};
    const int DR[5] = {1, 0, 2, 1, 1}, DP[5] = {1, 1, 1, 0, 2};

#pragma unroll
    for (int kc = 0; kc < 4; ++kc) {
#pragma unroll
        for (int tap = 0; tap < 5; ++tap) {
            const int ks = kc * 5 + tap;
            f16x8 bf[4];
#pragma unroll
            for (int nf = 0; nf < 4; ++nf)
                bf[nf] = *(const f16x8*)(wb + (size_t)ks * 4096 + nf * 512);
#pragma unroll
            for (int rr = 0; rr < 2; ++rr) {
                if (tap == 1 && rr == 0 && !topok) continue;
                if (tap == 2 && rr == 1 && !botok) continue;
                f16x8 af = *(const f16x8*)(rb[rr + DR[tap]] + loff[DP[tap]] + kc * 32);
#pragma unroll
                for (int nf = 0; nf < 4; ++nf)
                    acc[rr][nf] = __builtin_amdgcn_mfma_f32_16x16x32_f16(af, bf[nf], acc[rr][nf], 0, 0, 0);
            }
        }
    }

#pragma unroll
    for (int rr = 0; rr < 2; ++rr) {
        const size_t pxb = (size_t)(b * 256 + i0 + r0 + rr) * APX + j0;
#pragma unroll
        for (int nf = 0; nf < 4; ++nf) {
            const float bv = bias[n0 + nf * 16 + l16];
#pragma unroll
            for (int vi = 0; vi < 4; ++vi)
                outp[(pxb + quad * 4 + vi) * 128 + n0 + nf * 16 + l16] =
                    (_Float16)fmaxf(acc[rr][nf][vi] + bv, 0.f);
        }
    }
}

// ---------------- L4: 128 -> 6 (pad 16), M=128/block, W4 in LDS, fp32 out ---
__global__ __launch_bounds__(256, 2) void g4(
    const float* __restrict__ bias, float* __restrict__ outp)
{
    const _Float16* in = A1g + 128;
    __shared__ _Float16 Al[10 * 18 * 136];       // 48,960 B
    __shared__ _Float16 Bl[5 * 16 * 136];        // 21,760 B
    const int tid = threadIdx.x;
    const int j0 = blockIdx.x * 16, i0 = blockIdx.y * 8, b = blockIdx.z;

    for (int t = tid; t < 2880; t += 256) {      // A halo panel (pads give j-zeros)
        int r = t / 288, rem = t - r * 288, p = rem >> 4, q = rem & 15;
        int gi = i0 - 1 + r, gj = j0 - 1 + p;
        f16x8 v = {0, 0, 0, 0, 0, 0, 0, 0};
        if ((unsigned)gi < 256u)
            v = *(const f16x8*)&in[((size_t)(b * 256 + gi) * APX + gj) * 128 + q * 8];
        *(f16x8*)&Al[(r * 18 + p) * 136 + q * 8] = v;
    }
    for (int t = tid; t < 1280; t += 256) {      // W4 tile: [tap][oc16][ic]
        int to = t >> 4, q = t & 15;
        *(f16x8*)&Bl[to * 136 + q * 8] = *(const f16x8*)&W4g[to * 128 + q * 8];
    }
    __syncthreads();

    const int lane = tid & 63, w = tid >> 6;     // wave: rows {2w, 2w+1}
    const int l16 = lane & 15, quad = lane >> 4;
    f32x4 acc[2] = {};
    const int DR[5] = {1, 0, 2, 1, 1}, DP[5] = {1, 1, 1, 0, 2};

#pragma unroll
    for (int ks = 0; ks < 20; ++ks) {
        const int tap = ks >> 2, kc = ks & 3;
        const int koff = kc * 32 + quad * 8;
        f16x8 bf = *(const f16x8*)&Bl[(tap * 16 + l16) * 136 + koff];
#pragma unroll
        for (int mf = 0; mf < 2; ++mf) {
            f16x8 af = *(const f16x8*)&Al[((DR[tap] + 2 * w + mf) * 18 + DP[tap] + l16) * 136 + koff];
            acc[mf] = __builtin_amdgcn_mfma_f32_16x16x32_f16(af, bf, acc[mf], 0, 0, 0);
        }
    }

    if (l16 < 6) {
        const float bb = bias[l16];
#pragma unroll
        for (int mf = 0; mf < 2; ++mf) {
            const int i = i0 + 2 * w + mf;
#pragma unroll
            for (int vi = 0; vi < 4; ++vi) {
                int jj = j0 + quad * 4 + vi;
                outp[(((size_t)b * 6 + l16) << 16) + i * 256 + jj] = acc[mf][vi] + bb;
            }
        }
    }
}

extern "C" void kernel_launch(void* const* d_in, const int* in_sizes, int n_in,
                              void* d_out, int out_size, void* d_ws, size_t ws_size,
                              hipStream_t stream) {
    const float* x  = (const float*)d_in[0];
    const float* w1 = (const float*)d_in[1];
    const float* b1 = (const float*)d_in[2];
    const float* w2 = (const float*)d_in[3];
    const float* b2 = (const float*)d_in[4];
    const float* w3 = (const float*)d_in[5];
    const float* b3 = (const float*)d_in[6];
    const float* w4 = (const float*)d_in[7];
    const float* b4 = (const float*)d_in[8];
    float* out = (float*)d_out;
    (void)d_ws; (void)ws_size;                   // activations live in device globals

    prep<<<2745, 256, 0, stream>>>(w1, w2, w3, w4);
    g1<<<dim3(16, 32, 8), dim3(256, 1, 1), 0, stream>>>(x, b1);
    gmid<2><<<dim3(16, 64, 8), dim3(256, 1, 1), 0, stream>>>(b2);
    gmid<3><<<dim3(16, 64, 8), dim3(256, 1, 1), 0, stream>>>(b3);
    g4<<<dim3(16, 32, 8), dim3(256, 1, 1), 0, stream>>>(b4, out);
}